// Round 1
// baseline (1002.221 us; speedup 1.0000x reference)
//
#include <hip/hip_runtime.h>

typedef __bf16 bf16x8 __attribute__((ext_vector_type(8)));
typedef float f32x4 __attribute__((ext_vector_type(4)));
typedef unsigned short u16;

#define GEMM_BM 128
#define GEMM_BN 128
#define GEMM_BK 64
#define LDS_STRIDE 72  // 64 + 8 pad (bf16 elems) -> 144B row stride, spreads b128 reads over banks

__device__ __forceinline__ u16 f2bf(float f) {
  unsigned int u = __builtin_bit_cast(unsigned int, f);
  u += 0x7fff + ((u >> 16) & 1);   // RNE
  return (u16)(u >> 16);
}
__device__ __forceinline__ float bf2f(u16 s) {
  unsigned int u = ((unsigned int)s) << 16;
  return __builtin_bit_cast(float, u);
}
__device__ __forceinline__ void unp8(uint4 u, float* f) {
  f[0] = bf2f(u.x & 0xffff); f[1] = bf2f(u.x >> 16);
  f[2] = bf2f(u.y & 0xffff); f[3] = bf2f(u.y >> 16);
  f[4] = bf2f(u.z & 0xffff); f[5] = bf2f(u.z >> 16);
  f[6] = bf2f(u.w & 0xffff); f[7] = bf2f(u.w >> 16);
}
__device__ __forceinline__ uint4 pk8(const float* f) {
  uint4 u;
  u.x = (unsigned)f2bf(f[0]) | ((unsigned)f2bf(f[1]) << 16);
  u.y = (unsigned)f2bf(f[2]) | ((unsigned)f2bf(f[3]) << 16);
  u.z = (unsigned)f2bf(f[4]) | ((unsigned)f2bf(f[5]) << 16);
  u.w = (unsigned)f2bf(f[6]) | ((unsigned)f2bf(f[7]) << 16);
  return u;
}

// C[M,N] = alpha * A[M,K] * Bt[N,K]^T (+ bias_row[M]) (+ bias_col[N]) (+ residual)
// A, Bt bf16 (as u16). Output bf16 or fp32. All of M,N multiples of 128, K multiple of 64.
template <bool OUT_F32>
__global__ __launch_bounds__(256) void gemm_nt(
    const u16* __restrict__ A, int lda, unsigned long long sA,
    const u16* __restrict__ Bt, int ldb, unsigned long long sB,
    void* __restrict__ Cout, int ldc, unsigned long long sC,
    int K, float alpha,
    const float* __restrict__ bias_row, const float* __restrict__ bias_col,
    const float* __restrict__ residual, unsigned long long sRes) {
  __shared__ u16 As[GEMM_BM * LDS_STRIDE];
  __shared__ u16 Bs[GEMM_BN * LDS_STRIDE];

  const int t = threadIdx.x;
  const int bz = blockIdx.z;
  A  += (size_t)bz * sA;
  Bt += (size_t)bz * sB;
  const int m0 = blockIdx.x * GEMM_BM;
  const int n0 = blockIdx.y * GEMM_BN;

  // staging map: thread t loads 4 uint4 (64B) of row srow, chunk base scb
  const int srow = t >> 1;
  const int scb  = (t & 1) * 4;
  const uint4* gA = reinterpret_cast<const uint4*>(A  + (size_t)(m0 + srow) * lda);
  const uint4* gB = reinterpret_cast<const uint4*>(Bt + (size_t)(n0 + srow) * ldb);

  f32x4 acc[4][4] = {};

  const int lane = t & 63;
  const int wid  = t >> 6;
  const int wm   = (wid >> 1) * 64;
  const int wn   = (wid & 1) * 64;
  const int fr   = lane & 15;      // fragment row/col
  const int kg   = lane >> 4;      // k-group 0..3

  for (int k0 = 0; k0 < K; k0 += GEMM_BK) {
    uint4 ra[4], rb[4];
    const int kq = k0 >> 3;  // uint4 index
#pragma unroll
    for (int i = 0; i < 4; ++i) ra[i] = gA[kq + scb + i];
#pragma unroll
    for (int i = 0; i < 4; ++i) rb[i] = gB[kq + scb + i];
    __syncthreads();
#pragma unroll
    for (int i = 0; i < 4; ++i)
      *reinterpret_cast<uint4*>(&As[srow * LDS_STRIDE + (scb + i) * 8]) = ra[i];
#pragma unroll
    for (int i = 0; i < 4; ++i)
      *reinterpret_cast<uint4*>(&Bs[srow * LDS_STRIDE + (scb + i) * 8]) = rb[i];
    __syncthreads();

#pragma unroll
    for (int kk = 0; kk < 2; ++kk) {
      bf16x8 af[4], bfr[4];
#pragma unroll
      for (int m = 0; m < 4; ++m)
        af[m] = *reinterpret_cast<const bf16x8*>(
            &As[(wm + m * 16 + fr) * LDS_STRIDE + kk * 32 + kg * 8]);
#pragma unroll
      for (int n = 0; n < 4; ++n)
        bfr[n] = *reinterpret_cast<const bf16x8*>(
            &Bs[(wn + n * 16 + fr) * LDS_STRIDE + kk * 32 + kg * 8]);
#pragma unroll
      for (int m = 0; m < 4; ++m)
#pragma unroll
        for (int n = 0; n < 4; ++n)
          acc[m][n] = __builtin_amdgcn_mfma_f32_16x16x32_bf16(af[m], bfr[n], acc[m][n], 0, 0, 0);
    }
  }

  // epilogue: C/D layout col=lane&15, row=(lane>>4)*4+reg
  float* Cf = reinterpret_cast<float*>(Cout);
  u16*   Cb = reinterpret_cast<u16*>(Cout);
  const size_t cbase = (size_t)bz * sC;
  const size_t rbase = (size_t)bz * sRes;
  const int rq = (lane >> 4) * 4;
#pragma unroll
  for (int m = 0; m < 4; ++m) {
#pragma unroll
    for (int n = 0; n < 4; ++n) {
      const int gcol = n0 + wn + n * 16 + fr;
      const float bc = bias_col ? bias_col[gcol] : 0.0f;
#pragma unroll
      for (int r = 0; r < 4; ++r) {
        const int grow = m0 + wm + m * 16 + rq + r;
        float v = acc[m][n][r] * alpha + bc;
        if (bias_row) v += bias_row[grow];
        if (residual) v += residual[rbase + (size_t)grow * ldc + gcol];
        const size_t ci = cbase + (size_t)grow * ldc + gcol;
        if (OUT_F32) Cf[ci] = v; else Cb[ci] = f2bf(v);
      }
    }
  }
}

// GroupNorm: x fp32 [B,C,N] -> h_t bf16 [B,N,C].  One block per (group, batch).
__global__ __launch_bounds__(256) void groupnorm_k(
    const float* __restrict__ x, const float* __restrict__ gamma,
    const float* __restrict__ beta, u16* __restrict__ h_t, int C, int N) {
  const int g = blockIdx.x;  // 0..31
  const int b = blockIdx.y;
  const int t = threadIdx.x;
  const float* xb = x + ((size_t)b * C + g * 16) * N;

  float s = 0.f, q = 0.f;
  for (int c = 0; c < 16; ++c) {
    const float4* xr = reinterpret_cast<const float4*>(xb + (size_t)c * N);
    for (int j = t; j < N / 4; j += 256) {
      float4 v = xr[j];
      s += v.x + v.y + v.z + v.w;
      q += v.x * v.x + v.y * v.y + v.z * v.z + v.w * v.w;
    }
  }
#pragma unroll
  for (int o = 32; o > 0; o >>= 1) { s += __shfl_down(s, o); q += __shfl_down(q, o); }
  __shared__ float rs[4], rq[4], stats[2];
  const int lane = t & 63, wid = t >> 6;
  if (lane == 0) { rs[wid] = s; rq[wid] = q; }
  __syncthreads();
  if (t == 0) {
    float S = rs[0] + rs[1] + rs[2] + rs[3];
    float Q = rq[0] + rq[1] + rq[2] + rq[3];
    const float inv = 1.0f / (16.0f * (float)N);
    float mean = S * inv;
    float var = Q * inv - mean * mean;
    stats[0] = mean;
    stats[1] = rsqrtf(var + 1e-6f);
  }
  __syncthreads();
  const float mean = stats[0], rstd = stats[1];

  float gm[16], bt[16];
#pragma unroll
  for (int c = 0; c < 16; ++c) {
    gm[c] = gamma[g * 16 + c] * rstd;
    bt[c] = beta[g * 16 + c] - mean * gm[c];
  }
  u16* ho = h_t + (size_t)b * N * C + g * 16;
  for (int n = t; n < N; n += 256) {
    union { u16 us[16]; uint4 v4[2]; } pk;
#pragma unroll
    for (int c = 0; c < 16; ++c) {
      float v = xb[(size_t)c * N + n];
      pk.us[c] = f2bf(v * gm[c] + bt[c]);
    }
    uint4* dst = reinterpret_cast<uint4*>(ho + (size_t)n * C);
    dst[0] = pk.v4[0];
    dst[1] = pk.v4[1];
  }
}

// In-place row softmax over bf16 rows of length 4096. grid (4096, nbatch)
__global__ __launch_bounds__(256) void softmax_rows(u16* __restrict__ S) {
  const size_t row = (size_t)blockIdx.y * gridDim.x + blockIdx.x;
  uint4* rp4 = reinterpret_cast<uint4*>(S + row * 4096);
  const int t = threadIdx.x;
  uint4 u0 = rp4[t], u1 = rp4[t + 256];
  float f[16];
  unp8(u0, f); unp8(u1, f + 8);

  float mx = f[0];
#pragma unroll
  for (int i = 1; i < 16; ++i) mx = fmaxf(mx, f[i]);
#pragma unroll
  for (int o = 32; o > 0; o >>= 1) mx = fmaxf(mx, __shfl_down(mx, o));
  __shared__ float red[4], bc[2];
  const int lane = t & 63, wid = t >> 6;
  if (lane == 0) red[wid] = mx;
  __syncthreads();
  if (t == 0) bc[0] = fmaxf(fmaxf(red[0], red[1]), fmaxf(red[2], red[3]));
  __syncthreads();
  mx = bc[0];

  float sum = 0.f;
#pragma unroll
  for (int i = 0; i < 16; ++i) { f[i] = __expf(f[i] - mx); sum += f[i]; }
#pragma unroll
  for (int o = 32; o > 0; o >>= 1) sum += __shfl_down(sum, o);
  if (lane == 0) red[wid] = sum;
  __syncthreads();
  if (t == 0) bc[1] = 1.0f / (red[0] + red[1] + red[2] + red[3]);
  __syncthreads();
  const float inv = bc[1];
#pragma unroll
  for (int i = 0; i < 16; ++i) f[i] *= inv;
  rp4[t] = pk8(f);
  rp4[t + 256] = pk8(f + 8);
}

__global__ __launch_bounds__(256) void wcvt(const float* __restrict__ src,
                                            u16* __restrict__ dst, int n) {
  const int i = (blockIdx.x * 256 + threadIdx.x) * 8;
  if (i >= n) return;
  const float4* s4 = reinterpret_cast<const float4*>(src + i);
  float4 a = s4[0], b = s4[1];
  float f[8] = {a.x, a.y, a.z, a.w, b.x, b.y, b.z, b.w};
  *reinterpret_cast<uint4*>(dst + i) = pk8(f);
}

extern "C" void kernel_launch(void* const* d_in, const int* in_sizes, int n_in,
                              void* d_out, int out_size, void* d_ws, size_t ws_size,
                              hipStream_t stream) {
  const float* x     = (const float*)d_in[0];
  const float* gamma = (const float*)d_in[1];
  const float* beta  = (const float*)d_in[2];
  const float* wq    = (const float*)d_in[3];
  const float* bq    = (const float*)d_in[4];
  const float* wk    = (const float*)d_in[5];
  const float* bk    = (const float*)d_in[6];
  const float* wv    = (const float*)d_in[7];
  const float* bv    = (const float*)d_in[8];
  const float* wo    = (const float*)d_in[9];
  const float* bo    = (const float*)d_in[10];

  const int B = 4, C = 512, N = 4096;
  const size_t NC = (size_t)N * C;
  const size_t NN = (size_t)N * N;
  const size_t CC = (size_t)C * C;

  char* ws = (char*)d_ws;
  size_t off = 0;
  auto alloc = [&](size_t bytes) {
    size_t r = off;
    off = (off + bytes + 255) & ~(size_t)255;
    return r;
  };
  u16* wq_b = (u16*)(ws + alloc(CC * 2));
  u16* wk_b = (u16*)(ws + alloc(CC * 2));
  u16* wv_b = (u16*)(ws + alloc(CC * 2));
  u16* wo_b = (u16*)(ws + alloc(CC * 2));
  u16* h_t  = (u16*)(ws + alloc(B * NC * 2));
  u16* q_t  = (u16*)(ws + alloc(B * NC * 2));
  u16* k_t  = (u16*)(ws + alloc(B * NC * 2));
  u16* v_cn = (u16*)(ws + alloc(B * NC * 2));
  u16* o_t  = (u16*)(ws + alloc(B * NC * 2));
  const size_t base_need = off;

  int s_batched = 0;
  u16* S;
  if (ws_size >= base_need + B * NN * 2) {            // all-batch scores buffer
    S = (u16*)(ws + alloc(B * NN * 2));
    s_batched = 1;
  } else if (ws_size >= base_need + NN * 2) {         // per-batch scores buffer
    S = (u16*)(ws + alloc(NN * 2));
  } else {                                            // emergency: d_out (33.5MB) as scratch
    S = (u16*)d_out;                                  // final GEMM overwrites it at the end
  }

  // weights fp32 -> bf16
  wcvt<<<dim3(CC / 2048), 256, 0, stream>>>(wq, wq_b, (int)CC);
  wcvt<<<dim3(CC / 2048), 256, 0, stream>>>(wk, wk_b, (int)CC);
  wcvt<<<dim3(CC / 2048), 256, 0, stream>>>(wv, wv_b, (int)CC);
  wcvt<<<dim3(CC / 2048), 256, 0, stream>>>(wo, wo_b, (int)CC);

  // groupnorm -> h_t [b,n,c]
  groupnorm_k<<<dim3(32, B), 256, 0, stream>>>(x, gamma, beta, h_t, C, N);

  // q,k : [b,n,co] = h_t[b,n,ci] * w[co,ci]^T + b[co]
  dim3 gqk(N / 128, C / 128, B);
  gemm_nt<false><<<gqk, 256, 0, stream>>>(h_t, C, NC, wq_b, C, 0, q_t, C, NC,
                                          C, 1.0f, nullptr, bq, nullptr, 0);
  gemm_nt<false><<<gqk, 256, 0, stream>>>(h_t, C, NC, wk_b, C, 0, k_t, C, NC,
                                          C, 1.0f, nullptr, bk, nullptr, 0);
  // v : [b,co,n] = w[co,ci] * h_t[b,n,ci]^T + b[co]
  dim3 gv(C / 128, N / 128, B);
  gemm_nt<false><<<gv, 256, 0, stream>>>(wv_b, C, 0, h_t, C, NC, v_cn, N, NC,
                                         C, 1.0f, bv, nullptr, nullptr, 0);

  const float scale = 0.044194173824159216f;  // 512^-0.5
  if (s_batched) {
    dim3 gs(N / 128, N / 128, B);
    gemm_nt<false><<<gs, 256, 0, stream>>>(q_t, C, NC, k_t, C, NC, S, N, NN,
                                           C, scale, nullptr, nullptr, nullptr, 0);
    softmax_rows<<<dim3(N, B), 256, 0, stream>>>(S);
    dim3 go(N / 128, C / 128, B);
    gemm_nt<false><<<go, 256, 0, stream>>>(S, N, NN, v_cn, N, NC, o_t, C, NC,
                                           N, 1.0f, nullptr, nullptr, nullptr, 0);
  } else {
    for (int b = 0; b < B; ++b) {
      dim3 gs(N / 128, N / 128, 1);
      gemm_nt<false><<<gs, 256, 0, stream>>>(q_t + b * NC, C, 0, k_t + b * NC, C, 0,
                                             S, N, 0, C, scale, nullptr, nullptr, nullptr, 0);
      softmax_rows<<<dim3(N, 1), 256, 0, stream>>>(S);
      dim3 go(N / 128, C / 128, 1);
      gemm_nt<false><<<go, 256, 0, stream>>>(S, N, 0, v_cn + b * NC, N, 0,
                                             o_t + b * NC, C, 0, N, 1.0f,
                                             nullptr, nullptr, nullptr, 0);
    }
  }

  // out[b,co,n] = wo[co,ci] * o_t[b,n,ci]^T + bo[co] + x[b,co,n]   (fp32)
  dim3 gf(C / 128, N / 128, B);
  gemm_nt<true><<<gf, 256, 0, stream>>>(wo_b, C, 0, o_t, C, NC, d_out, N, NC,
                                        C, 1.0f, bo, nullptr, x, NC);
}

// Round 2
// 420.300 us; speedup vs baseline: 2.3845x; 2.3845x over previous
//
#include <hip/hip_runtime.h>

typedef __bf16 bf16x8 __attribute__((ext_vector_type(8)));
typedef float f32x4 __attribute__((ext_vector_type(4)));
typedef unsigned short u16;

__device__ __forceinline__ u16 f2bf(float f) {
  unsigned int u = __builtin_bit_cast(unsigned int, f);
  u += 0x7fff + ((u >> 16) & 1);   // RNE
  return (u16)(u >> 16);
}
__device__ __forceinline__ float bf2f(u16 s) {
  unsigned int u = ((unsigned int)s) << 16;
  return __builtin_bit_cast(float, u);
}
__device__ __forceinline__ void unp8(uint4 u, float* f) {
  f[0] = bf2f(u.x & 0xffff); f[1] = bf2f(u.x >> 16);
  f[2] = bf2f(u.y & 0xffff); f[3] = bf2f(u.y >> 16);
  f[4] = bf2f(u.z & 0xffff); f[5] = bf2f(u.z >> 16);
  f[6] = bf2f(u.w & 0xffff); f[7] = bf2f(u.w >> 16);
}
__device__ __forceinline__ uint4 pk8(const float* f) {
  uint4 u;
  u.x = (unsigned)f2bf(f[0]) | ((unsigned)f2bf(f[1]) << 16);
  u.y = (unsigned)f2bf(f[2]) | ((unsigned)f2bf(f[3]) << 16);
  u.z = (unsigned)f2bf(f[4]) | ((unsigned)f2bf(f[5]) << 16);
  u.w = (unsigned)f2bf(f[6]) | ((unsigned)f2bf(f[7]) << 16);
  return u;
}

// async global->LDS, 16B per lane. LDS dest = wave-uniform base + lane*16 (HW).
__device__ __forceinline__ void gl_lds16(const u16* g, u16* l) {
  __builtin_amdgcn_global_load_lds(
      (const __attribute__((address_space(1))) void*)g,
      (__attribute__((address_space(3))) void*)l, 16, 0, 0);
}

// C[M,N] = alpha * A[M,K] * Bt[N,K]^T (+ bias_row[M]) (+ bias_col[N]) (+ residual)
// A, Bt bf16 (u16). M,N multiples of 128, K multiple of 64.
// m97 structure: 128x128 tile, BK=64, global_load_lds width-16 staging, linear LDS,
// 2 barriers per K-step. bf16 output goes through an LDS-staged coalesced epilogue.
template <bool OUT_F32>
__global__ __launch_bounds__(256) void gemm_nt(
    const u16* __restrict__ A, int lda, unsigned long long sA,
    const u16* __restrict__ Bt, int ldb, unsigned long long sB,
    void* __restrict__ Cout, int ldc, unsigned long long sC,
    int K, float alpha,
    const float* __restrict__ bias_row, const float* __restrict__ bias_col,
    const float* __restrict__ residual, unsigned long long sRes) {
  __shared__ u16 lds[128 * 128];     // 32KB: As = [0,8192), Bs = [8192,16384)
  u16* As = lds;
  u16* Bs = lds + 8192;

  const int t = threadIdx.x;
  const int bz = blockIdx.z;
  A  += (size_t)bz * sA;
  Bt += (size_t)bz * sB;
  const int m0 = blockIdx.x * 128;
  const int n0 = blockIdx.y * 128;

  const int lane = t & 63;
  const int w = t >> 6;

  // staging geometry: wave w owns rows [w*32, w*32+32), 4 issues x 8 rows each.
  // lane l -> row +(l>>3), col (l&7)*8 ; matches HW linear LDS fill (lane*16B).
  const int srow = w * 32 + (lane >> 3);
  const int scol = (lane & 7) * 8;
  const u16* gA = A  + (size_t)(m0 + srow) * lda + scol;
  const u16* gB = Bt + (size_t)(n0 + srow) * ldb + scol;
  u16* lA = As + w * 2048;           // + i*512 per issue (8 rows * 64)
  u16* lB = Bs + w * 2048;

  f32x4 acc[4][4] = {};
  const int wm = (w >> 1) * 64;
  const int wn = (w & 1) * 64;
  const int fr = lane & 15;          // fragment row/col
  const int kg = lane >> 4;          // k-group 0..3

  for (int k0 = 0; k0 < K; k0 += 64) {
    __syncthreads();                 // previous compute done, LDS reusable
#pragma unroll
    for (int i = 0; i < 4; ++i) {
      gl_lds16(gA + (size_t)(i * 8) * lda + k0, lA + i * 512);
      gl_lds16(gB + (size_t)(i * 8) * ldb + k0, lB + i * 512);
    }
    __syncthreads();                 // vmcnt(0) drain -> tile ready

#pragma unroll
    for (int kk = 0; kk < 2; ++kk) {
      bf16x8 af[4], bfr[4];
#pragma unroll
      for (int m = 0; m < 4; ++m)
        af[m] = *reinterpret_cast<const bf16x8*>(
            &As[(wm + m * 16 + fr) * 64 + kk * 32 + kg * 8]);
#pragma unroll
      for (int n = 0; n < 4; ++n)
        bfr[n] = *reinterpret_cast<const bf16x8*>(
            &Bs[(wn + n * 16 + fr) * 64 + kk * 32 + kg * 8]);
#pragma unroll
      for (int m = 0; m < 4; ++m)
#pragma unroll
        for (int n = 0; n < 4; ++n)
          acc[m][n] = __builtin_amdgcn_mfma_f32_16x16x32_bf16(af[m], bfr[n], acc[m][n], 0, 0, 0);
    }
  }

  // epilogue: C/D layout col=lane&15, row=(lane>>4)*4+reg
  const size_t cbase = (size_t)bz * sC;
  const size_t rbase = (size_t)bz * sRes;
  const int rq = kg * 4;

  if (OUT_F32) {
    float* Cf = reinterpret_cast<float*>(Cout);
#pragma unroll
    for (int m = 0; m < 4; ++m) {
#pragma unroll
      for (int n = 0; n < 4; ++n) {
        const int gcol = n0 + wn + n * 16 + fr;
        const float bc = bias_col ? bias_col[gcol] : 0.0f;
#pragma unroll
        for (int r = 0; r < 4; ++r) {
          const int grow = m0 + wm + m * 16 + rq + r;
          float v = acc[m][n][r] * alpha + bc;
          if (bias_row) v += bias_row[grow];
          if (residual) v += residual[rbase + (size_t)grow * ldc + gcol];
          Cf[cbase + (size_t)grow * ldc + gcol] = v;
        }
      }
    }
  } else {
    // stage C tile (bf16) in LDS, then write coalesced uint4 rows
    __syncthreads();                 // all waves done reading As/Bs
#pragma unroll
    for (int m = 0; m < 4; ++m) {
#pragma unroll
      for (int n = 0; n < 4; ++n) {
        const int gcol = n0 + wn + n * 16 + fr;
        const float bc = bias_col ? bias_col[gcol] : 0.0f;
#pragma unroll
        for (int r = 0; r < 4; ++r) {
          const int grow = m0 + wm + m * 16 + rq + r;
          float v = acc[m][n][r] * alpha + bc;
          if (bias_row) v += bias_row[grow];
          lds[(wm + m * 16 + rq + r) * 128 + (wn + n * 16 + fr)] = f2bf(v);
        }
      }
    }
    __syncthreads();
    u16* Cb = reinterpret_cast<u16*>(Cout);
#pragma unroll
    for (int j = 0; j < 8; ++j) {
      const int off = (j * 256 + t) * 8;      // elem in 128x128 tile
      const int row = off >> 7, col = off & 127;
      *reinterpret_cast<uint4*>(&Cb[cbase + (size_t)(m0 + row) * ldc + (n0 + col)]) =
          *reinterpret_cast<const uint4*>(&lds[off]);
    }
  }
}

// GroupNorm: x fp32 [B,C,N] -> h_t bf16 [B,N,C].  One block per (group, batch).
__global__ __launch_bounds__(256) void groupnorm_k(
    const float* __restrict__ x, const float* __restrict__ gamma,
    const float* __restrict__ beta, u16* __restrict__ h_t, int C, int N) {
  const int g = blockIdx.x;  // 0..31
  const int b = blockIdx.y;
  const int t = threadIdx.x;
  const float* xb = x + ((size_t)b * C + g * 16) * N;

  float s = 0.f, q = 0.f;
  for (int c = 0; c < 16; ++c) {
    const float4* xr = reinterpret_cast<const float4*>(xb + (size_t)c * N);
    for (int j = t; j < N / 4; j += 256) {
      float4 v = xr[j];
      s += v.x + v.y + v.z + v.w;
      q += v.x * v.x + v.y * v.y + v.z * v.z + v.w * v.w;
    }
  }
#pragma unroll
  for (int o = 32; o > 0; o >>= 1) { s += __shfl_down(s, o); q += __shfl_down(q, o); }
  __shared__ float rs[4], rqs[4], stats[2];
  const int lane = t & 63, wid = t >> 6;
  if (lane == 0) { rs[wid] = s; rqs[wid] = q; }
  __syncthreads();
  if (t == 0) {
    float S = rs[0] + rs[1] + rs[2] + rs[3];
    float Q = rqs[0] + rqs[1] + rqs[2] + rqs[3];
    const float inv = 1.0f / (16.0f * (float)N);
    float mean = S * inv;
    float var = Q * inv - mean * mean;
    stats[0] = mean;
    stats[1] = rsqrtf(var + 1e-6f);
  }
  __syncthreads();
  const float mean = stats[0], rstd = stats[1];

  float gm[16], bt[16];
#pragma unroll
  for (int c = 0; c < 16; ++c) {
    gm[c] = gamma[g * 16 + c] * rstd;
    bt[c] = beta[g * 16 + c] - mean * gm[c];
  }
  u16* ho = h_t + (size_t)b * N * C + g * 16;
  for (int n = t; n < N; n += 256) {
    union { u16 us[16]; uint4 v4[2]; } pk;
#pragma unroll
    for (int c = 0; c < 16; ++c) {
      float v = xb[(size_t)c * N + n];
      pk.us[c] = f2bf(v * gm[c] + bt[c]);
    }
    uint4* dst = reinterpret_cast<uint4*>(ho + (size_t)n * C);
    dst[0] = pk.v4[0];
    dst[1] = pk.v4[1];
  }
}

// In-place row softmax over bf16 rows of length 4096. grid (4096, nbatch)
__global__ __launch_bounds__(256) void softmax_rows(u16* __restrict__ S) {
  const size_t row = (size_t)blockIdx.y * gridDim.x + blockIdx.x;
  uint4* rp4 = reinterpret_cast<uint4*>(S + row * 4096);
  const int t = threadIdx.x;
  uint4 u0 = rp4[t], u1 = rp4[t + 256];
  float f[16];
  unp8(u0, f); unp8(u1, f + 8);

  float mx = f[0];
#pragma unroll
  for (int i = 1; i < 16; ++i) mx = fmaxf(mx, f[i]);
#pragma unroll
  for (int o = 32; o > 0; o >>= 1) mx = fmaxf(mx, __shfl_down(mx, o));
  __shared__ float red[4], bc[2];
  const int lane = t & 63, wid = t >> 6;
  if (lane == 0) red[wid] = mx;
  __syncthreads();
  if (t == 0) bc[0] = fmaxf(fmaxf(red[0], red[1]), fmaxf(red[2], red[3]));
  __syncthreads();
  mx = bc[0];

  float sum = 0.f;
#pragma unroll
  for (int i = 0; i < 16; ++i) { f[i] = __expf(f[i] - mx); sum += f[i]; }
#pragma unroll
  for (int o = 32; o > 0; o >>= 1) sum += __shfl_down(sum, o);
  if (lane == 0) red[wid] = sum;
  __syncthreads();
  if (t == 0) bc[1] = 1.0f / (red[0] + red[1] + red[2] + red[3]);
  __syncthreads();
  const float inv = bc[1];
#pragma unroll
  for (int i = 0; i < 16; ++i) f[i] *= inv;
  rp4[t] = pk8(f);
  rp4[t + 256] = pk8(f + 8);
}

__global__ __launch_bounds__(256) void wcvt(const float* __restrict__ src,
                                            u16* __restrict__ dst, int n) {
  const int i = (blockIdx.x * 256 + threadIdx.x) * 8;
  if (i >= n) return;
  const float4* s4 = reinterpret_cast<const float4*>(src + i);
  float4 a = s4[0], b = s4[1];
  float f[8] = {a.x, a.y, a.z, a.w, b.x, b.y, b.z, b.w};
  *reinterpret_cast<uint4*>(dst + i) = pk8(f);
}

extern "C" void kernel_launch(void* const* d_in, const int* in_sizes, int n_in,
                              void* d_out, int out_size, void* d_ws, size_t ws_size,
                              hipStream_t stream) {
  const float* x     = (const float*)d_in[0];
  const float* gamma = (const float*)d_in[1];
  const float* beta  = (const float*)d_in[2];
  const float* wq    = (const float*)d_in[3];
  const float* bq    = (const float*)d_in[4];
  const float* wk    = (const float*)d_in[5];
  const float* bk    = (const float*)d_in[6];
  const float* wv    = (const float*)d_in[7];
  const float* bv    = (const float*)d_in[8];
  const float* wo    = (const float*)d_in[9];
  const float* bo    = (const float*)d_in[10];

  const int B = 4, C = 512, N = 4096;
  const size_t NC = (size_t)N * C;
  const size_t NN = (size_t)N * N;
  const size_t CC = (size_t)C * C;

  char* ws = (char*)d_ws;
  size_t off = 0;
  auto alloc = [&](size_t bytes) {
    size_t r = off;
    off = (off + bytes + 255) & ~(size_t)255;
    return r;
  };
  u16* wq_b = (u16*)(ws + alloc(CC * 2));
  u16* wk_b = (u16*)(ws + alloc(CC * 2));
  u16* wv_b = (u16*)(ws + alloc(CC * 2));
  u16* wo_b = (u16*)(ws + alloc(CC * 2));
  u16* h_t  = (u16*)(ws + alloc(B * NC * 2));
  u16* q_t  = (u16*)(ws + alloc(B * NC * 2));
  u16* k_t  = (u16*)(ws + alloc(B * NC * 2));
  u16* v_cn = (u16*)(ws + alloc(B * NC * 2));
  u16* o_t  = (u16*)(ws + alloc(B * NC * 2));
  const size_t base_need = off;

  int s_batched = 0;
  u16* S;
  if (ws_size >= base_need + B * NN * 2) {            // all-batch scores buffer
    S = (u16*)(ws + alloc(B * NN * 2));
    s_batched = 1;
  } else if (ws_size >= base_need + NN * 2) {         // per-batch scores buffer
    S = (u16*)(ws + alloc(NN * 2));
  } else {                                            // emergency: d_out (33.5MB) as scratch
    S = (u16*)d_out;                                  // final GEMM overwrites it at the end
  }

  // weights fp32 -> bf16
  wcvt<<<dim3(CC / 2048), 256, 0, stream>>>(wq, wq_b, (int)CC);
  wcvt<<<dim3(CC / 2048), 256, 0, stream>>>(wk, wk_b, (int)CC);
  wcvt<<<dim3(CC / 2048), 256, 0, stream>>>(wv, wv_b, (int)CC);
  wcvt<<<dim3(CC / 2048), 256, 0, stream>>>(wo, wo_b, (int)CC);

  // groupnorm -> h_t [b,n,c]
  groupnorm_k<<<dim3(32, B), 256, 0, stream>>>(x, gamma, beta, h_t, C, N);

  // q,k : [b,n,co] = h_t[b,n,ci] * w[co,ci]^T + b[co]
  dim3 gqk(N / 128, C / 128, B);
  gemm_nt<false><<<gqk, 256, 0, stream>>>(h_t, C, NC, wq_b, C, 0, q_t, C, NC,
                                          C, 1.0f, nullptr, bq, nullptr, 0);
  gemm_nt<false><<<gqk, 256, 0, stream>>>(h_t, C, NC, wk_b, C, 0, k_t, C, NC,
                                          C, 1.0f, nullptr, bk, nullptr, 0);
  // v : [b,co,n] = w[co,ci] * h_t[b,n,ci]^T + b[co]
  dim3 gv(C / 128, N / 128, B);
  gemm_nt<false><<<gv, 256, 0, stream>>>(wv_b, C, 0, h_t, C, NC, v_cn, N, NC,
                                         C, 1.0f, bv, nullptr, nullptr, 0);

  const float scale = 0.044194173824159216f;  // 512^-0.5
  if (s_batched) {
    dim3 gs(N / 128, N / 128, B);
    gemm_nt<false><<<gs, 256, 0, stream>>>(q_t, C, NC, k_t, C, NC, S, N, NN,
                                           C, scale, nullptr, nullptr, nullptr, 0);
    softmax_rows<<<dim3(N, B), 256, 0, stream>>>(S);
    dim3 go(N / 128, C / 128, B);
    gemm_nt<false><<<go, 256, 0, stream>>>(S, N, NN, v_cn, N, NC, o_t, C, NC,
                                           N, 1.0f, nullptr, nullptr, nullptr, 0);
  } else {
    for (int b = 0; b < B; ++b) {
      dim3 gs(N / 128, N / 128, 1);
      gemm_nt<false><<<gs, 256, 0, stream>>>(q_t + b * NC, C, 0, k_t + b * NC, C, 0,
                                             S, N, 0, C, scale, nullptr, nullptr, nullptr, 0);
      softmax_rows<<<dim3(N, 1), 256, 0, stream>>>(S);
      dim3 go(N / 128, C / 128, 1);
      gemm_nt<false><<<go, 256, 0, stream>>>(S, N, 0, v_cn + b * NC, N, 0,
                                             o_t + b * NC, C, 0, N, 1.0f,
                                             nullptr, nullptr, nullptr, 0);
    }
  }

  // out[b,co,n] = wo[co,ci] * o_t[b,n,ci]^T + bo[co] + x[b,co,n]   (fp32)
  dim3 gf(C / 128, N / 128, B);
  gemm_nt<true><<<gf, 256, 0, stream>>>(wo_b, C, 0, o_t, C, NC, d_out, N, NC,
                                        C, 1.0f, bo, nullptr, x, NC);
}

// Round 3
// 383.815 us; speedup vs baseline: 2.6112x; 1.0951x over previous
//
#include <hip/hip_runtime.h>

typedef __bf16 bf16x8 __attribute__((ext_vector_type(8)));
typedef float f32x4 __attribute__((ext_vector_type(4)));
typedef unsigned short u16;

__device__ __forceinline__ u16 f2bf(float f) {
  unsigned int u = __builtin_bit_cast(unsigned int, f);
  u += 0x7fff + ((u >> 16) & 1);   // RNE
  return (u16)(u >> 16);
}
__device__ __forceinline__ float bf2f(u16 s) {
  unsigned int u = ((unsigned int)s) << 16;
  return __builtin_bit_cast(float, u);
}
__device__ __forceinline__ void unp8(uint4 u, float* f) {
  f[0] = bf2f(u.x & 0xffff); f[1] = bf2f(u.x >> 16);
  f[2] = bf2f(u.y & 0xffff); f[3] = bf2f(u.y >> 16);
  f[4] = bf2f(u.z & 0xffff); f[5] = bf2f(u.z >> 16);
  f[6] = bf2f(u.w & 0xffff); f[7] = bf2f(u.w >> 16);
}
__device__ __forceinline__ uint4 pk8(const float* f) {
  uint4 u;
  u.x = (unsigned)f2bf(f[0]) | ((unsigned)f2bf(f[1]) << 16);
  u.y = (unsigned)f2bf(f[2]) | ((unsigned)f2bf(f[3]) << 16);
  u.z = (unsigned)f2bf(f[4]) | ((unsigned)f2bf(f[5]) << 16);
  u.w = (unsigned)f2bf(f[6]) | ((unsigned)f2bf(f[7]) << 16);
  return u;
}

// async global->LDS, 16B per lane. LDS dest = wave-uniform base + lane*16 (HW).
__device__ __forceinline__ void gl_lds16(const u16* g, u16* l) {
  __builtin_amdgcn_global_load_lds(
      (const __attribute__((address_space(1))) void*)g,
      (__attribute__((address_space(3))) void*)l, 16, 0, 0);
}

// ---------------------------------------------------------------------------
// 256x256 8-phase GEMM (T1+T2+T3+T4+T5): C[M,N] = alpha * A[M,K] * Bt[N,K]^T
// bf16 in/out. M,N multiples of 256, K multiple of 128 (NKT even).
// 8 waves (2Mx4N), per-wave C = 128x64. LDS 128KB: 2 slots x {A0,A1,B0,B1}
// half-tiles (128 rows x 64 cols bf16 = 16KB each).
// Swizzle: lds(row, c16) holds global(row, c16 ^ (row&7)); applied via
// pre-swizzled global source (gl_lds writes linearly) + XOR on ds_read.
// Counted vmcnt(2) at phases 3 and 7 only; never vmcnt(0) in the main loop.
// ---------------------------------------------------------------------------
__global__ __launch_bounds__(512, 2) void gemm_nt256(
    const u16* __restrict__ A, int lda, unsigned long long sA,
    const u16* __restrict__ Bt, int ldb, unsigned long long sB,
    u16* __restrict__ Cout, int ldc, unsigned long long sC,
    int K, float alpha, int tn) {
  __shared__ u16 lds[2][4][8192];   // [slot][region A0,A1,B0,B1][128 rows x 64]

  const int t = threadIdx.x;
  const int lane = t & 63;
  const int w = t >> 6;
  const int bz = blockIdx.z;
  A  += (size_t)bz * sA;
  Bt += (size_t)bz * sB;

  // T1: bijective XCD swizzle (nwg % 8 == 0 guaranteed by launch)
  const int nwg = gridDim.x;
  const int flat = blockIdx.x;
  const int wg = (flat & 7) * (nwg >> 3) + (flat >> 3);
  const int m0 = (wg / tn) * 256;
  const int n0 = (wg % tn) * 256;

  const int NKT = K >> 6;

  // staging source per lane: row = +sr, col16 = (lane&7) ^ sr  (pre-swizzle)
  const int sr = lane >> 3;
  const int sc = ((lane & 7) ^ sr) * 8;
  const u16* gA = A  + (size_t)(m0 + w * 16 + sr) * lda + sc;
  const u16* gB = Bt + (size_t)(n0 + w * 16 + sr) * ldb + sc;
  const size_t a128 = (size_t)128 * lda, b128 = (size_t)128 * ldb;
  const size_t a8 = (size_t)8 * lda, b8 = (size_t)8 * ldb;
  const int lws = w * 1024;          // wave's slice within a region (elems)

  auto stage = [&](int slot, int region, int kt) {
    kt = kt < NKT ? kt : NKT - 1;    // tail clamp (keeps vmcnt counts uniform)
    u16* l = &lds[slot][region][lws];
    if (region < 2) {
      const u16* g = gA + (region ? a128 : 0) + (size_t)kt * 64;
      gl_lds16(g, l);
      gl_lds16(g + a8, l + 512);
    } else {
      const u16* g = gB + (region == 3 ? b128 : 0) + (size_t)kt * 64;
      gl_lds16(g, l);
      gl_lds16(g + b8, l + 512);
    }
  };

  const int wr = w >> 2, wc = w & 3;
  const int fr = lane & 15, kg = lane >> 4;
  const int frx = (fr & 7) << 4;     // byte-XOR for swizzled reads

  f32x4 acc[8][4] = {};
  bf16x8 af[4][2], bq[2][2];

#define LDA_(s, qm)                                                            \
  {                                                                            \
    const u16* Ab = &lds[s][0][0];                                             \
    _Pragma("unroll") for (int m = 0; m < 4; ++m) {                            \
      const int R = wr * 128 + (qm) * 64 + m * 16 + fr;                        \
      _Pragma("unroll") for (int kk = 0; kk < 2; ++kk)                         \
          af[m][kk] = *reinterpret_cast<const bf16x8*>(                        \
              Ab + R * 64 + (((kk * 64 + kg * 16) ^ frx) >> 1));               \
    }                                                                          \
  }
#define LDB_(s, qn)                                                            \
  {                                                                            \
    const u16* Bb = &lds[s][2][0];                                             \
    _Pragma("unroll") for (int n = 0; n < 2; ++n) {                            \
      const int R = wc * 64 + (qn) * 32 + n * 16 + fr;                         \
      _Pragma("unroll") for (int kk = 0; kk < 2; ++kk)                         \
          bq[n][kk] = *reinterpret_cast<const bf16x8*>(                        \
              Bb + R * 64 + (((kk * 64 + kg * 16) ^ frx) >> 1));               \
    }                                                                          \
  }
#define PH(s, qm, qn, DOA, DOB, ss, rr, kt, VM)                                \
  {                                                                            \
    if (DOA) LDA_(s, qm)                                                       \
    if (DOB) LDB_(s, qn)                                                       \
    stage(ss, rr, kt);                                                         \
    __builtin_amdgcn_s_barrier();                                              \
    asm volatile("s_waitcnt lgkmcnt(0)" ::: "memory");                         \
    __builtin_amdgcn_s_setprio(1);                                             \
    _Pragma("unroll") for (int kk = 0; kk < 2; ++kk)                           \
    _Pragma("unroll") for (int m = 0; m < 4; ++m)                              \
    _Pragma("unroll") for (int n = 0; n < 2; ++n)                              \
        acc[(qm)*4 + m][(qn)*2 + n] = __builtin_amdgcn_mfma_f32_16x16x32_bf16( \
            af[m][kk], bq[n][kk], acc[(qm)*4 + m][(qn)*2 + n], 0, 0, 0);       \
    __builtin_amdgcn_s_setprio(0);                                             \
    if (VM) asm volatile("s_waitcnt vmcnt(2)" ::: "memory");                   \
    __builtin_amdgcn_s_barrier();                                              \
  }

  // prologue: tile0 full + A0 of tile1 (10 loads/wave); wait until tile0 done
  stage(0, 0, 0); stage(0, 1, 0); stage(0, 2, 0); stage(0, 3, 0);
  stage(1, 0, 1);
  asm volatile("s_waitcnt vmcnt(2)" ::: "memory");
  __builtin_amdgcn_s_barrier();

  for (int j = 0; j < (NKT >> 1); ++j) {
    const int k1 = 2 * j + 1, k2 = 2 * j + 2, k3 = 2 * j + 3;
    PH(0, 0, 0, 1, 1, 1, 1, k1, 0)   // p0: stage slot1.A1(k1)
    PH(0, 0, 1, 0, 1, 1, 2, k1, 0)   // p1: slot1.B0(k1)
    PH(0, 1, 1, 1, 0, 1, 3, k1, 0)   // p2: slot1.B1(k1)
    PH(0, 1, 0, 0, 1, 0, 0, k2, 1)   // p3: slot0.A0(k2) + vmcnt(2)
    PH(1, 0, 0, 1, 1, 0, 1, k2, 0)   // p4: slot0.A1(k2)
    PH(1, 0, 1, 0, 1, 0, 2, k2, 0)   // p5: slot0.B0(k2)
    PH(1, 1, 1, 1, 0, 0, 3, k2, 0)   // p6: slot0.B1(k2)
    PH(1, 1, 0, 0, 1, 1, 0, k3, 1)   // p7: slot1.A0(k3) + vmcnt(2)
  }
#undef PH
#undef LDB_
#undef LDA_

  // epilogue: drain tail DMAs, stage C tile bf16 in LDS, coalesced store
  __syncthreads();
  u16* cs = &lds[0][0][0];
#pragma unroll
  for (int a = 0; a < 8; ++a)
#pragma unroll
    for (int b = 0; b < 4; ++b) {
      const int row = wr * 128 + a * 16 + kg * 4;
      const int col = wc * 64 + b * 16 + fr;
#pragma unroll
      for (int r = 0; r < 4; ++r)
        cs[(row + r) * 256 + col] = f2bf(acc[a][b][r] * alpha);
    }
  __syncthreads();
  const size_t cb = (size_t)bz * sC;
#pragma unroll
  for (int it = 0; it < 16; ++it) {
    const int off = (it * 512 + t) * 8;
    const int row = off >> 8, col = off & 255;
    *reinterpret_cast<uint4*>(&Cout[cb + (size_t)(m0 + row) * ldc + (n0 + col)]) =
        *reinterpret_cast<const uint4*>(&cs[off]);
  }
}

// ---------------------------------------------------------------------------
// 128x128 m97-structure GEMM (kept for qkv/proj shapes)
// ---------------------------------------------------------------------------
template <bool OUT_F32>
__global__ __launch_bounds__(256) void gemm_nt(
    const u16* __restrict__ A, int lda, unsigned long long sA,
    const u16* __restrict__ Bt, int ldb, unsigned long long sB,
    void* __restrict__ Cout, int ldc, unsigned long long sC,
    int K, float alpha,
    const float* __restrict__ bias_row, const float* __restrict__ bias_col,
    const float* __restrict__ residual, unsigned long long sRes) {
  __shared__ u16 lds[128 * 128];
  u16* As = lds;
  u16* Bs = lds + 8192;

  const int t = threadIdx.x;
  const int bz = blockIdx.z;
  A  += (size_t)bz * sA;
  Bt += (size_t)bz * sB;
  const int m0 = blockIdx.x * 128;
  const int n0 = blockIdx.y * 128;

  const int lane = t & 63;
  const int w = t >> 6;

  const int srow = w * 32 + (lane >> 3);
  const int scol = (lane & 7) * 8;
  const u16* gA = A  + (size_t)(m0 + srow) * lda + scol;
  const u16* gB = Bt + (size_t)(n0 + srow) * ldb + scol;
  u16* lA = As + w * 2048;
  u16* lB = Bs + w * 2048;

  f32x4 acc[4][4] = {};
  const int wm = (w >> 1) * 64;
  const int wn = (w & 1) * 64;
  const int fr = lane & 15;
  const int kg = lane >> 4;

  for (int k0 = 0; k0 < K; k0 += 64) {
    __syncthreads();
#pragma unroll
    for (int i = 0; i < 4; ++i) {
      gl_lds16(gA + (size_t)(i * 8) * lda + k0, lA + i * 512);
      gl_lds16(gB + (size_t)(i * 8) * ldb + k0, lB + i * 512);
    }
    __syncthreads();

#pragma unroll
    for (int kk = 0; kk < 2; ++kk) {
      bf16x8 af[4], bfr[4];
#pragma unroll
      for (int m = 0; m < 4; ++m)
        af[m] = *reinterpret_cast<const bf16x8*>(
            &As[(wm + m * 16 + fr) * 64 + kk * 32 + kg * 8]);
#pragma unroll
      for (int n = 0; n < 4; ++n)
        bfr[n] = *reinterpret_cast<const bf16x8*>(
            &Bs[(wn + n * 16 + fr) * 64 + kk * 32 + kg * 8]);
#pragma unroll
      for (int m = 0; m < 4; ++m)
#pragma unroll
        for (int n = 0; n < 4; ++n)
          acc[m][n] = __builtin_amdgcn_mfma_f32_16x16x32_bf16(af[m], bfr[n], acc[m][n], 0, 0, 0);
    }
  }

  const size_t cbase = (size_t)bz * sC;
  const size_t rbase = (size_t)bz * sRes;
  const int rq = kg * 4;

  if (OUT_F32) {
    float* Cf = reinterpret_cast<float*>(Cout);
#pragma unroll
    for (int m = 0; m < 4; ++m) {
#pragma unroll
      for (int n = 0; n < 4; ++n) {
        const int gcol = n0 + wn + n * 16 + fr;
        const float bc = bias_col ? bias_col[gcol] : 0.0f;
#pragma unroll
        for (int r = 0; r < 4; ++r) {
          const int grow = m0 + wm + m * 16 + rq + r;
          float v = acc[m][n][r] * alpha + bc;
          if (bias_row) v += bias_row[grow];
          if (residual) v += residual[rbase + (size_t)grow * ldc + gcol];
          Cf[cbase + (size_t)grow * ldc + gcol] = v;
        }
      }
    }
  } else {
    __syncthreads();
#pragma unroll
    for (int m = 0; m < 4; ++m) {
#pragma unroll
      for (int n = 0; n < 4; ++n) {
        const int gcol = n0 + wn + n * 16 + fr;
        const float bc = bias_col ? bias_col[gcol] : 0.0f;
#pragma unroll
        for (int r = 0; r < 4; ++r) {
          const int grow = m0 + wm + m * 16 + rq + r;
          float v = acc[m][n][r] * alpha + bc;
          if (bias_row) v += bias_row[grow];
          lds[(wm + m * 16 + rq + r) * 128 + (wn + n * 16 + fr)] = f2bf(v);
        }
      }
    }
    __syncthreads();
    u16* Cb = reinterpret_cast<u16*>(Cout);
#pragma unroll
    for (int j = 0; j < 8; ++j) {
      const int off = (j * 256 + t) * 8;
      const int row = off >> 7, col = off & 127;
      *reinterpret_cast<uint4*>(&Cb[cbase + (size_t)(m0 + row) * ldc + (n0 + col)]) =
          *reinterpret_cast<const uint4*>(&lds[off]);
    }
  }
}

// GroupNorm: x fp32 [B,C,N] -> h_t bf16 [B,N,C].  One block per (group, batch).
__global__ __launch_bounds__(256) void groupnorm_k(
    const float* __restrict__ x, const float* __restrict__ gamma,
    const float* __restrict__ beta, u16* __restrict__ h_t, int C, int N) {
  const int g = blockIdx.x;
  const int b = blockIdx.y;
  const int t = threadIdx.x;
  const float* xb = x + ((size_t)b * C + g * 16) * N;

  float s = 0.f, q = 0.f;
  for (int c = 0; c < 16; ++c) {
    const float4* xr = reinterpret_cast<const float4*>(xb + (size_t)c * N);
    for (int j = t; j < N / 4; j += 256) {
      float4 v = xr[j];
      s += v.x + v.y + v.z + v.w;
      q += v.x * v.x + v.y * v.y + v.z * v.z + v.w * v.w;
    }
  }
#pragma unroll
  for (int o = 32; o > 0; o >>= 1) { s += __shfl_down(s, o); q += __shfl_down(q, o); }
  __shared__ float rs[4], rqs[4], stats[2];
  const int lane = t & 63, wid = t >> 6;
  if (lane == 0) { rs[wid] = s; rqs[wid] = q; }
  __syncthreads();
  if (t == 0) {
    float S = rs[0] + rs[1] + rs[2] + rs[3];
    float Q = rqs[0] + rqs[1] + rqs[2] + rqs[3];
    const float inv = 1.0f / (16.0f * (float)N);
    float mean = S * inv;
    float var = Q * inv - mean * mean;
    stats[0] = mean;
    stats[1] = rsqrtf(var + 1e-6f);
  }
  __syncthreads();
  const float mean = stats[0], rstd = stats[1];

  float gm[16], bt[16];
#pragma unroll
  for (int c = 0; c < 16; ++c) {
    gm[c] = gamma[g * 16 + c] * rstd;
    bt[c] = beta[g * 16 + c] - mean * gm[c];
  }
  u16* ho = h_t + (size_t)b * N * C + g * 16;
  for (int n = t; n < N; n += 256) {
    union { u16 us[16]; uint4 v4[2]; } pk;
#pragma unroll
    for (int c = 0; c < 16; ++c) {
      float v = xb[(size_t)c * N + n];
      pk.us[c] = f2bf(v * gm[c] + bt[c]);
    }
    uint4* dst = reinterpret_cast<uint4*>(ho + (size_t)n * C);
    dst[0] = pk.v4[0];
    dst[1] = pk.v4[1];
  }
}

// In-place row softmax over bf16 rows of length 4096. grid (4096, nbatch)
__global__ __launch_bounds__(256) void softmax_rows(u16* __restrict__ S) {
  const size_t row = (size_t)blockIdx.y * gridDim.x + blockIdx.x;
  uint4* rp4 = reinterpret_cast<uint4*>(S + row * 4096);
  const int t = threadIdx.x;
  uint4 u0 = rp4[t], u1 = rp4[t + 256];
  float f[16];
  unp8(u0, f); unp8(u1, f + 8);

  float mx = f[0];
#pragma unroll
  for (int i = 1; i < 16; ++i) mx = fmaxf(mx, f[i]);
#pragma unroll
  for (int o = 32; o > 0; o >>= 1) mx = fmaxf(mx, __shfl_down(mx, o));
  __shared__ float red[4], bc[2];
  const int lane = t & 63, wid = t >> 6;
  if (lane == 0) red[wid] = mx;
  __syncthreads();
  if (t == 0) bc[0] = fmaxf(fmaxf(red[0], red[1]), fmaxf(red[2], red[3]));
  __syncthreads();
  mx = bc[0];

  float sum = 0.f;
#pragma unroll
  for (int i = 0; i < 16; ++i) { f[i] = __expf(f[i] - mx); sum += f[i]; }
#pragma unroll
  for (int o = 32; o > 0; o >>= 1) sum += __shfl_down(sum, o);
  if (lane == 0) red[wid] = sum;
  __syncthreads();
  if (t == 0) bc[1] = 1.0f / (red[0] + red[1] + red[2] + red[3]);
  __syncthreads();
  const float inv = bc[1];
#pragma unroll
  for (int i = 0; i < 16; ++i) f[i] *= inv;
  rp4[t] = pk8(f);
  rp4[t + 256] = pk8(f + 8);
}

__global__ __launch_bounds__(256) void wcvt(const float* __restrict__ src,
                                            u16* __restrict__ dst, int n) {
  const int i = (blockIdx.x * 256 + threadIdx.x) * 8;
  if (i >= n) return;
  const float4* s4 = reinterpret_cast<const float4*>(src + i);
  float4 a = s4[0], b = s4[1];
  float f[8] = {a.x, a.y, a.z, a.w, b.x, b.y, b.z, b.w};
  *reinterpret_cast<uint4*>(dst + i) = pk8(f);
}

extern "C" void kernel_launch(void* const* d_in, const int* in_sizes, int n_in,
                              void* d_out, int out_size, void* d_ws, size_t ws_size,
                              hipStream_t stream) {
  const float* x     = (const float*)d_in[0];
  const float* gamma = (const float*)d_in[1];
  const float* beta  = (const float*)d_in[2];
  const float* wq    = (const float*)d_in[3];
  const float* bq    = (const float*)d_in[4];
  const float* wk    = (const float*)d_in[5];
  const float* bk    = (const float*)d_in[6];
  const float* wv    = (const float*)d_in[7];
  const float* bv    = (const float*)d_in[8];
  const float* wo    = (const float*)d_in[9];
  const float* bo    = (const float*)d_in[10];

  const int B = 4, C = 512, N = 4096;
  const size_t NC = (size_t)N * C;
  const size_t NN = (size_t)N * N;
  const size_t CC = (size_t)C * C;

  char* ws = (char*)d_ws;
  size_t off = 0;
  auto alloc = [&](size_t bytes) {
    size_t r = off;
    off = (off + bytes + 255) & ~(size_t)255;
    return r;
  };
  u16* wq_b = (u16*)(ws + alloc(CC * 2));
  u16* wk_b = (u16*)(ws + alloc(CC * 2));
  u16* wv_b = (u16*)(ws + alloc(CC * 2));
  u16* wo_b = (u16*)(ws + alloc(CC * 2));
  u16* h_t  = (u16*)(ws + alloc(B * NC * 2));
  u16* q_t  = (u16*)(ws + alloc(B * NC * 2));
  u16* k_t  = (u16*)(ws + alloc(B * NC * 2));
  u16* v_cn = (u16*)(ws + alloc(B * NC * 2));
  u16* o_t  = (u16*)(ws + alloc(B * NC * 2));
  const size_t base_need = off;

  int s_batched = 0;
  u16* S;
  if (ws_size >= base_need + B * NN * 2) {
    S = (u16*)(ws + alloc(B * NN * 2));
    s_batched = 1;
  } else if (ws_size >= base_need + NN * 2) {
    S = (u16*)(ws + alloc(NN * 2));
  } else {
    S = (u16*)d_out;
  }

  // weights fp32 -> bf16
  wcvt<<<dim3(CC / 2048), 256, 0, stream>>>(wq, wq_b, (int)CC);
  wcvt<<<dim3(CC / 2048), 256, 0, stream>>>(wk, wk_b, (int)CC);
  wcvt<<<dim3(CC / 2048), 256, 0, stream>>>(wv, wv_b, (int)CC);
  wcvt<<<dim3(CC / 2048), 256, 0, stream>>>(wo, wo_b, (int)CC);

  // groupnorm -> h_t [b,n,c]
  groupnorm_k<<<dim3(32, B), 256, 0, stream>>>(x, gamma, beta, h_t, C, N);

  // q,k : [b,n,co] = h_t[b,n,ci] * w[co,ci]^T + b[co]
  dim3 gqk(N / 128, C / 128, B);
  gemm_nt<false><<<gqk, 256, 0, stream>>>(h_t, C, NC, wq_b, C, 0, q_t, C, NC,
                                          C, 1.0f, nullptr, bq, nullptr, 0);
  gemm_nt<false><<<gqk, 256, 0, stream>>>(h_t, C, NC, wk_b, C, 0, k_t, C, NC,
                                          C, 1.0f, nullptr, bk, nullptr, 0);
  // v : [b,co,n] = w[co,ci] * h_t[b,n,ci]^T + b[co]
  dim3 gv(C / 128, N / 128, B);
  gemm_nt<false><<<gv, 256, 0, stream>>>(wv_b, C, 0, h_t, C, NC, v_cn, N, NC,
                                         C, 1.0f, bv, nullptr, nullptr, 0);

  const float scale = 0.044194173824159216f;  // 512^-0.5
  if (s_batched) {
    // QK: S[n,m] = scale * q_t[n,:] . k_t[m,:]   (256^2 8-phase, tn = 16)
    gemm_nt256<<<dim3((N / 256) * (N / 256), 1, B), 512, 0, stream>>>(
        q_t, C, NC, k_t, C, NC, S, N, NN, C, scale, N / 256);
    softmax_rows<<<dim3(N, B), 256, 0, stream>>>(S);
    // PV: o_t[n,c] = S[n,:] . v_cn[c,:]          (256^2 8-phase, tn = 2)
    gemm_nt256<<<dim3((N / 256) * (C / 256), 1, B), 512, 0, stream>>>(
        S, N, NN, v_cn, N, NC, o_t, C, NC, N, 1.0f, C / 256);
  } else {
    for (int b = 0; b < B; ++b) {
      gemm_nt256<<<dim3((N / 256) * (N / 256), 1, 1), 512, 0, stream>>>(
          q_t + b * NC, C, 0, k_t + b * NC, C, 0, S, N, 0, C, scale, N / 256);
      softmax_rows<<<dim3(N, 1), 256, 0, stream>>>(S);
      gemm_nt256<<<dim3((N / 256) * (C / 256), 1, 1), 512, 0, stream>>>(
          S, N, 0, v_cn + b * NC, N, 0, o_t + b * NC, C, 0, N, 1.0f, C / 256);
    }
  }

  // out[b,co,n] = wo[co,ci] * o_t[b,n,ci]^T + bo[co] + x[b,co,n]   (fp32)
  dim3 gf(C / 128, N / 128, B);
  gemm_nt<true><<<gf, 256, 0, stream>>>(wo_b, C, 0, o_t, C, NC, d_out, N, NC,
                                        C, 1.0f, bo, nullptr, x, NC);
}

// Round 4
// 329.816 us; speedup vs baseline: 3.0387x; 1.1637x over previous
//
#include <hip/hip_runtime.h>

typedef __bf16 bf16x8 __attribute__((ext_vector_type(8)));
typedef float f32x4 __attribute__((ext_vector_type(4)));
typedef unsigned short u16;

__device__ __forceinline__ u16 f2bf(float f) {
  unsigned int u = __builtin_bit_cast(unsigned int, f);
  u += 0x7fff + ((u >> 16) & 1);   // RNE
  return (u16)(u >> 16);
}
__device__ __forceinline__ float bf2f(u16 s) {
  unsigned int u = ((unsigned int)s) << 16;
  return __builtin_bit_cast(float, u);
}
__device__ __forceinline__ void unp8(uint4 u, float* f) {
  f[0] = bf2f(u.x & 0xffff); f[1] = bf2f(u.x >> 16);
  f[2] = bf2f(u.y & 0xffff); f[3] = bf2f(u.y >> 16);
  f[4] = bf2f(u.z & 0xffff); f[5] = bf2f(u.z >> 16);
  f[6] = bf2f(u.w & 0xffff); f[7] = bf2f(u.w >> 16);
}
__device__ __forceinline__ uint4 pk8(const float* f) {
  uint4 u;
  u.x = (unsigned)f2bf(f[0]) | ((unsigned)f2bf(f[1]) << 16);
  u.y = (unsigned)f2bf(f[2]) | ((unsigned)f2bf(f[3]) << 16);
  u.z = (unsigned)f2bf(f[4]) | ((unsigned)f2bf(f[5]) << 16);
  u.w = (unsigned)f2bf(f[6]) | ((unsigned)f2bf(f[7]) << 16);
  return u;
}

// async global->LDS, 16B per lane. LDS dest = wave-uniform base + lane*16 (HW).
__device__ __forceinline__ void gl_lds16(const u16* g, u16* l) {
  __builtin_amdgcn_global_load_lds(
      (const __attribute__((address_space(1))) void*)g,
      (__attribute__((address_space(3))) void*)l, 16, 0, 0);
}

// ---------------------------------------------------------------------------
// 256x256 8-phase GEMM (T1+T2+T3+T4+T5): C = alpha*A*Bt^T (+bias_col), bf16.
// grid = (ntiles, nsplit, batch); blockIdx.y = K-split index: this block
// handles K elems [y*K, (y+1)*K) and writes to Cout + y*sSplit.
// ---------------------------------------------------------------------------
__global__ __launch_bounds__(512, 2) void gemm_nt256(
    const u16* __restrict__ A, int lda, unsigned long long sA,
    const u16* __restrict__ Bt, int ldb, unsigned long long sB,
    u16* __restrict__ Cout, int ldc, unsigned long long sC,
    unsigned long long sSplit, int K, float alpha, int tn,
    const float* __restrict__ bias_col) {
  __shared__ u16 lds[2][4][8192];   // [slot][region A0,A1,B0,B1][128 rows x 64]

  const int t = threadIdx.x;
  const int lane = t & 63;
  const int w = t >> 6;
  const int bz = blockIdx.z;
  A  += (size_t)bz * sA + (size_t)blockIdx.y * K;
  Bt += (size_t)bz * sB + (size_t)blockIdx.y * K;
  Cout += (size_t)blockIdx.y * sSplit;

  // T1: bijective XCD swizzle (nwg % 8 == 0 guaranteed by launch)
  const int nwg = gridDim.x;
  const int flat = blockIdx.x;
  const int wg = (flat & 7) * (nwg >> 3) + (flat >> 3);
  const int m0 = (wg / tn) * 256;
  const int n0 = (wg % tn) * 256;

  const int NKT = K >> 6;

  // staging source per lane: row = +sr, col16 = (lane&7) ^ sr  (pre-swizzle)
  const int sr = lane >> 3;
  const int sc = ((lane & 7) ^ sr) * 8;
  const u16* gA = A  + (size_t)(m0 + w * 16 + sr) * lda + sc;
  const u16* gB = Bt + (size_t)(n0 + w * 16 + sr) * ldb + sc;
  const size_t a128 = (size_t)128 * lda, b128 = (size_t)128 * ldb;
  const size_t a8 = (size_t)8 * lda, b8 = (size_t)8 * ldb;
  const int lws = w * 1024;          // wave's slice within a region (elems)

  auto stage = [&](int slot, int region, int kt) {
    kt = kt < NKT ? kt : NKT - 1;    // tail clamp (keeps vmcnt counts uniform)
    u16* l = &lds[slot][region][lws];
    if (region < 2) {
      const u16* g = gA + (region ? a128 : 0) + (size_t)kt * 64;
      gl_lds16(g, l);
      gl_lds16(g + a8, l + 512);
    } else {
      const u16* g = gB + (region == 3 ? b128 : 0) + (size_t)kt * 64;
      gl_lds16(g, l);
      gl_lds16(g + b8, l + 512);
    }
  };

  const int wr = w >> 2, wc = w & 3;
  const int fr = lane & 15, kg = lane >> 4;
  const int frx = (fr & 7) << 4;     // byte-XOR for swizzled reads

  f32x4 acc[8][4] = {};
  bf16x8 af[4][2], bq[2][2];

#define LDA_(s, qm)                                                            \
  {                                                                            \
    const u16* Ab = &lds[s][0][0];                                             \
    _Pragma("unroll") for (int m = 0; m < 4; ++m) {                            \
      const int R = wr * 128 + (qm) * 64 + m * 16 + fr;                        \
      _Pragma("unroll") for (int kk = 0; kk < 2; ++kk)                         \
          af[m][kk] = *reinterpret_cast<const bf16x8*>(                        \
              Ab + R * 64 + (((kk * 64 + kg * 16) ^ frx) >> 1));               \
    }                                                                          \
  }
#define LDB_(s, qn)                                                            \
  {                                                                            \
    const u16* Bb = &lds[s][2][0];                                             \
    _Pragma("unroll") for (int n = 0; n < 2; ++n) {                            \
      const int R = wc * 64 + (qn) * 32 + n * 16 + fr;                         \
      _Pragma("unroll") for (int kk = 0; kk < 2; ++kk)                         \
          bq[n][kk] = *reinterpret_cast<const bf16x8*>(                        \
              Bb + R * 64 + (((kk * 64 + kg * 16) ^ frx) >> 1));               \
    }                                                                          \
  }
#define PH(s, qm, qn, DOA, DOB, ss, rr, kt, VM)                                \
  {                                                                            \
    if (DOA) LDA_(s, qm)                                                       \
    if (DOB) LDB_(s, qn)                                                       \
    stage(ss, rr, kt);                                                         \
    __builtin_amdgcn_s_barrier();                                              \
    asm volatile("s_waitcnt lgkmcnt(0)" ::: "memory");                         \
    __builtin_amdgcn_s_setprio(1);                                             \
    _Pragma("unroll") for (int kk = 0; kk < 2; ++kk)                           \
    _Pragma("unroll") for (int m = 0; m < 4; ++m)                              \
    _Pragma("unroll") for (int n = 0; n < 2; ++n)                              \
        acc[(qm)*4 + m][(qn)*2 + n] = __builtin_amdgcn_mfma_f32_16x16x32_bf16( \
            af[m][kk], bq[n][kk], acc[(qm)*4 + m][(qn)*2 + n], 0, 0, 0);       \
    __builtin_amdgcn_s_setprio(0);                                             \
    if (VM) asm volatile("s_waitcnt vmcnt(2)" ::: "memory");                   \
    __builtin_amdgcn_s_barrier();                                              \
  }

  // prologue: tile0 full + A0 of tile1 (10 loads/wave); wait until tile0 done
  stage(0, 0, 0); stage(0, 1, 0); stage(0, 2, 0); stage(0, 3, 0);
  stage(1, 0, 1);
  asm volatile("s_waitcnt vmcnt(2)" ::: "memory");
  __builtin_amdgcn_s_barrier();

  for (int j = 0; j < (NKT >> 1); ++j) {
    const int k1 = 2 * j + 1, k2 = 2 * j + 2, k3 = 2 * j + 3;
    PH(0, 0, 0, 1, 1, 1, 1, k1, 0)   // p0: stage slot1.A1(k1)
    PH(0, 0, 1, 0, 1, 1, 2, k1, 0)   // p1: slot1.B0(k1)
    PH(0, 1, 1, 1, 0, 1, 3, k1, 0)   // p2: slot1.B1(k1)
    PH(0, 1, 0, 0, 1, 0, 0, k2, 1)   // p3: slot0.A0(k2) + vmcnt(2)
    PH(1, 0, 0, 1, 1, 0, 1, k2, 0)   // p4: slot0.A1(k2)
    PH(1, 0, 1, 0, 1, 0, 2, k2, 0)   // p5: slot0.B0(k2)
    PH(1, 1, 1, 1, 0, 0, 3, k2, 0)   // p6: slot0.B1(k2)
    PH(1, 1, 0, 0, 1, 1, 0, k3, 1)   // p7: slot1.A0(k3) + vmcnt(2)
  }
#undef PH
#undef LDB_
#undef LDA_

  // epilogue: drain tail DMAs, stage C tile bf16 in LDS, coalesced store
  __syncthreads();
  u16* cs = &lds[0][0][0];
#pragma unroll
  for (int a = 0; a < 8; ++a)
#pragma unroll
    for (int b = 0; b < 4; ++b) {
      const int col = wc * 64 + b * 16 + fr;
      const float bc = bias_col ? bias_col[n0 + col] : 0.0f;
      const int row = wr * 128 + a * 16 + kg * 4;
#pragma unroll
      for (int r = 0; r < 4; ++r)
        cs[(row + r) * 256 + col] = f2bf(acc[a][b][r] * alpha + bc);
    }
  __syncthreads();
  const size_t cb = (size_t)bz * sC;
#pragma unroll
  for (int it = 0; it < 16; ++it) {
    const int off = (it * 512 + t) * 8;
    const int row = off >> 8, col = off & 255;
    *reinterpret_cast<uint4*>(&Cout[cb + (size_t)(m0 + row) * ldc + (n0 + col)]) =
        *reinterpret_cast<const uint4*>(&cs[off]);
  }
}

// ---------------------------------------------------------------------------
// 128x128 m97-structure GEMM (v projection, final proj w/ fp32+residual)
// ---------------------------------------------------------------------------
template <bool OUT_F32>
__global__ __launch_bounds__(256) void gemm_nt(
    const u16* __restrict__ A, int lda, unsigned long long sA,
    const u16* __restrict__ Bt, int ldb, unsigned long long sB,
    void* __restrict__ Cout, int ldc, unsigned long long sC,
    int K, float alpha,
    const float* __restrict__ bias_row, const float* __restrict__ bias_col,
    const float* __restrict__ residual, unsigned long long sRes) {
  __shared__ u16 lds[128 * 128];
  u16* As = lds;
  u16* Bs = lds + 8192;

  const int t = threadIdx.x;
  const int bz = blockIdx.z;
  A  += (size_t)bz * sA;
  Bt += (size_t)bz * sB;
  const int m0 = blockIdx.x * 128;
  const int n0 = blockIdx.y * 128;

  const int lane = t & 63;
  const int w = t >> 6;

  const int srow = w * 32 + (lane >> 3);
  const int scol = (lane & 7) * 8;
  const u16* gA = A  + (size_t)(m0 + srow) * lda + scol;
  const u16* gB = Bt + (size_t)(n0 + srow) * ldb + scol;
  u16* lA = As + w * 2048;
  u16* lB = Bs + w * 2048;

  f32x4 acc[4][4] = {};
  const int wm = (w >> 1) * 64;
  const int wn = (w & 1) * 64;
  const int fr = lane & 15;
  const int kg = lane >> 4;

  for (int k0 = 0; k0 < K; k0 += 64) {
    __syncthreads();
#pragma unroll
    for (int i = 0; i < 4; ++i) {
      gl_lds16(gA + (size_t)(i * 8) * lda + k0, lA + i * 512);
      gl_lds16(gB + (size_t)(i * 8) * ldb + k0, lB + i * 512);
    }
    __syncthreads();

#pragma unroll
    for (int kk = 0; kk < 2; ++kk) {
      bf16x8 af[4], bfr[4];
#pragma unroll
      for (int m = 0; m < 4; ++m)
        af[m] = *reinterpret_cast<const bf16x8*>(
            &As[(wm + m * 16 + fr) * 64 + kk * 32 + kg * 8]);
#pragma unroll
      for (int n = 0; n < 4; ++n)
        bfr[n] = *reinterpret_cast<const bf16x8*>(
            &Bs[(wn + n * 16 + fr) * 64 + kk * 32 + kg * 8]);
#pragma unroll
      for (int m = 0; m < 4; ++m)
#pragma unroll
        for (int n = 0; n < 4; ++n)
          acc[m][n] = __builtin_amdgcn_mfma_f32_16x16x32_bf16(af[m], bfr[n], acc[m][n], 0, 0, 0);
    }
  }

  const size_t cbase = (size_t)bz * sC;
  const size_t rbase = (size_t)bz * sRes;
  const int rq = kg * 4;

  if (OUT_F32) {
    // LDS-staged fp32 epilogue: 2 rounds of 64x128 (32KB), coalesced float4
    // writes with bias_row/residual applied in the coalesced pass.
    float* Cf = reinterpret_cast<float*>(Cout);
    float* lf = reinterpret_cast<float*>(lds);   // 64 x 128 fp32 = 32 KB
#pragma unroll
    for (int h = 0; h < 2; ++h) {
      __syncthreads();
      if ((wm >> 6) == h) {
#pragma unroll
        for (int m = 0; m < 4; ++m)
#pragma unroll
          for (int n = 0; n < 4; ++n) {
            const float bc = bias_col ? bias_col[n0 + wn + n * 16 + fr] : 0.0f;
#pragma unroll
            for (int r = 0; r < 4; ++r)
              lf[(m * 16 + rq + r) * 128 + (wn + n * 16 + fr)] =
                  acc[m][n][r] * alpha + bc;
          }
      }
      __syncthreads();
#pragma unroll
      for (int it = 0; it < 8; ++it) {
        const int off = (it * 256 + t) * 4;
        const int row = off >> 7, col = off & 127;
        const int grow = m0 + h * 64 + row, gcol = n0 + col;
        float4 v = *reinterpret_cast<const float4*>(&lf[off]);
        if (bias_row) {
          const float br = bias_row[grow];
          v.x += br; v.y += br; v.z += br; v.w += br;
        }
        if (residual) {
          const float4 rx = *reinterpret_cast<const float4*>(
              &residual[rbase + (size_t)grow * ldc + gcol]);
          v.x += rx.x; v.y += rx.y; v.z += rx.z; v.w += rx.w;
        }
        *reinterpret_cast<float4*>(&Cf[cbase + (size_t)grow * ldc + gcol]) = v;
      }
    }
  } else {
    __syncthreads();
#pragma unroll
    for (int m = 0; m < 4; ++m) {
#pragma unroll
      for (int n = 0; n < 4; ++n) {
        const int gcol = n0 + wn + n * 16 + fr;
        const float bc = bias_col ? bias_col[gcol] : 0.0f;
#pragma unroll
        for (int r = 0; r < 4; ++r) {
          const int grow = m0 + wm + m * 16 + rq + r;
          float v = acc[m][n][r] * alpha + bc;
          if (bias_row) v += bias_row[grow];
          lds[(wm + m * 16 + rq + r) * 128 + (wn + n * 16 + fr)] = f2bf(v);
        }
      }
    }
    __syncthreads();
    u16* Cb = reinterpret_cast<u16*>(Cout);
#pragma unroll
    for (int j = 0; j < 8; ++j) {
      const int off = (j * 256 + t) * 8;
      const int row = off >> 7, col = off & 127;
      *reinterpret_cast<uint4*>(&Cb[cbase + (size_t)(m0 + row) * ldc + (n0 + col)]) =
          *reinterpret_cast<const uint4*>(&lds[off]);
    }
  }
}

// GroupNorm: x fp32 [B,C,N] -> h_t bf16 [B,N,C].  One block per (group, batch).
__global__ __launch_bounds__(256) void groupnorm_k(
    const float* __restrict__ x, const float* __restrict__ gamma,
    const float* __restrict__ beta, u16* __restrict__ h_t, int C, int N) {
  const int g = blockIdx.x;
  const int b = blockIdx.y;
  const int t = threadIdx.x;
  const float* xb = x + ((size_t)b * C + g * 16) * N;

  float s = 0.f, q = 0.f;
  for (int c = 0; c < 16; ++c) {
    const float4* xr = reinterpret_cast<const float4*>(xb + (size_t)c * N);
    for (int j = t; j < N / 4; j += 256) {
      float4 v = xr[j];
      s += v.x + v.y + v.z + v.w;
      q += v.x * v.x + v.y * v.y + v.z * v.z + v.w * v.w;
    }
  }
#pragma unroll
  for (int o = 32; o > 0; o >>= 1) { s += __shfl_down(s, o); q += __shfl_down(q, o); }
  __shared__ float rs[4], rqs[4], stats[2];
  const int lane = t & 63, wid = t >> 6;
  if (lane == 0) { rs[wid] = s; rqs[wid] = q; }
  __syncthreads();
  if (t == 0) {
    float S = rs[0] + rs[1] + rs[2] + rs[3];
    float Q = rqs[0] + rqs[1] + rqs[2] + rqs[3];
    const float inv = 1.0f / (16.0f * (float)N);
    float mean = S * inv;
    float var = Q * inv - mean * mean;
    stats[0] = mean;
    stats[1] = rsqrtf(var + 1e-6f);
  }
  __syncthreads();
  const float mean = stats[0], rstd = stats[1];

  float gm[16], bt[16];
#pragma unroll
  for (int c = 0; c < 16; ++c) {
    gm[c] = gamma[g * 16 + c] * rstd;
    bt[c] = beta[g * 16 + c] - mean * gm[c];
  }
  u16* ho = h_t + (size_t)b * N * C + g * 16;
  for (int n = t; n < N; n += 256) {
    union { u16 us[16]; uint4 v4[2]; } pk;
#pragma unroll
    for (int c = 0; c < 16; ++c) {
      float v = xb[(size_t)c * N + n];
      pk.us[c] = f2bf(v * gm[c] + bt[c]);
    }
    uint4* dst = reinterpret_cast<uint4*>(ho + (size_t)n * C);
    dst[0] = pk.v4[0];
    dst[1] = pk.v4[1];
  }
}

// In-place row softmax over bf16 rows of length 4096. grid (4096, nbatch)
__global__ __launch_bounds__(256) void softmax_rows(u16* __restrict__ S) {
  const size_t row = (size_t)blockIdx.y * gridDim.x + blockIdx.x;
  uint4* rp4 = reinterpret_cast<uint4*>(S + row * 4096);
  const int t = threadIdx.x;
  uint4 u0 = rp4[t], u1 = rp4[t + 256];
  float f[16];
  unp8(u0, f); unp8(u1, f + 8);

  float mx = f[0];
#pragma unroll
  for (int i = 1; i < 16; ++i) mx = fmaxf(mx, f[i]);
#pragma unroll
  for (int o = 32; o > 0; o >>= 1) mx = fmaxf(mx, __shfl_down(mx, o));
  __shared__ float red[4], bc[2];
  const int lane = t & 63, wid = t >> 6;
  if (lane == 0) red[wid] = mx;
  __syncthreads();
  if (t == 0) bc[0] = fmaxf(fmaxf(red[0], red[1]), fmaxf(red[2], red[3]));
  __syncthreads();
  mx = bc[0];

  float sum = 0.f;
#pragma unroll
  for (int i = 0; i < 16; ++i) { f[i] = __expf(f[i] - mx); sum += f[i]; }
#pragma unroll
  for (int o = 32; o > 0; o >>= 1) sum += __shfl_down(sum, o);
  if (lane == 0) red[wid] = sum;
  __syncthreads();
  if (t == 0) bc[1] = 1.0f / (red[0] + red[1] + red[2] + red[3]);
  __syncthreads();
  const float inv = bc[1];
#pragma unroll
  for (int i = 0; i < 16; ++i) f[i] *= inv;
  rp4[t] = pk8(f);
  rp4[t + 256] = pk8(f + 8);
}

__global__ __launch_bounds__(256) void wcvt(const float* __restrict__ src,
                                            u16* __restrict__ dst, int n) {
  const int i = (blockIdx.x * 256 + threadIdx.x) * 8;
  if (i >= n) return;
  const float4* s4 = reinterpret_cast<const float4*>(src + i);
  float4 a = s4[0], b = s4[1];
  float f[8] = {a.x, a.y, a.z, a.w, b.x, b.y, b.z, b.w};
  *reinterpret_cast<uint4*>(dst + i) = pk8(f);
}

// o[i] = bf16( p[i] + p[n+i] )  -- sum of two bf16 split-K partials
__global__ __launch_bounds__(256) void reduce_pv(const u16* __restrict__ p,
                                                 u16* __restrict__ o, int n) {
  const int i = (blockIdx.x * 256 + threadIdx.x) * 8;
  if (i >= n) return;
  uint4 a = *reinterpret_cast<const uint4*>(p + i);
  uint4 b = *reinterpret_cast<const uint4*>(p + n + i);
  float fa[8], fb[8];
  unp8(a, fa); unp8(b, fb);
#pragma unroll
  for (int j = 0; j < 8; ++j) fa[j] += fb[j];
  *reinterpret_cast<uint4*>(o + i) = pk8(fa);
}

// concat two fp32 vectors of length n
__global__ __launch_bounds__(256) void bcat2(const float* __restrict__ a,
                                             const float* __restrict__ b,
                                             float* __restrict__ o, int n) {
  const int i = blockIdx.x * 256 + threadIdx.x;
  if (i < n) o[i] = a[i];
  else if (i < 2 * n) o[i] = b[i - n];
}

extern "C" void kernel_launch(void* const* d_in, const int* in_sizes, int n_in,
                              void* d_out, int out_size, void* d_ws, size_t ws_size,
                              hipStream_t stream) {
  const float* x     = (const float*)d_in[0];
  const float* gamma = (const float*)d_in[1];
  const float* beta  = (const float*)d_in[2];
  const float* wq    = (const float*)d_in[3];
  const float* bq    = (const float*)d_in[4];
  const float* wk    = (const float*)d_in[5];
  const float* bk    = (const float*)d_in[6];
  const float* wv    = (const float*)d_in[7];
  const float* bv    = (const float*)d_in[8];
  const float* wo    = (const float*)d_in[9];
  const float* bo    = (const float*)d_in[10];

  const int B = 4, C = 512, N = 4096;
  const size_t NC = (size_t)N * C;
  const size_t NN = (size_t)N * N;
  const size_t CC = (size_t)C * C;

  char* ws = (char*)d_ws;
  size_t off = 0;
  auto alloc = [&](size_t bytes) {
    size_t r = off;
    off = (off + bytes + 255) & ~(size_t)255;
    return r;
  };
  u16* wq_b = (u16*)(ws + alloc(CC * 2));   // wq_b, wk_b contiguous: [wq;wk] rows
  u16* wk_b = (u16*)(ws + alloc(CC * 2));
  u16* wv_b = (u16*)(ws + alloc(CC * 2));
  u16* wo_b = (u16*)(ws + alloc(CC * 2));
  float* bqk = (float*)(ws + alloc(1024 * 4));
  u16* h_t  = (u16*)(ws + alloc(B * NC * 2));
  u16* qk_t = (u16*)(ws + alloc(B * N * 1024 * 2));  // q|k; reused as PV partials
  u16* v_cn = (u16*)(ws + alloc(B * NC * 2));
  u16* o_t  = (u16*)(ws + alloc(B * NC * 2));
  const size_t base_need = off;

  int s_batched = 0;
  u16* S;
  if (ws_size >= base_need + B * NN * 2) {
    S = (u16*)(ws + alloc(B * NN * 2));
    s_batched = 1;
  } else if (ws_size >= base_need + NN * 2) {
    S = (u16*)(ws + alloc(NN * 2));
  } else {
    S = (u16*)d_out;
  }
  u16* o_part = qk_t;   // 2 x B*NC bf16 == B*N*1024 bf16; qk_t dead after QK

  // weights fp32 -> bf16 ; bias concat
  wcvt<<<dim3(CC / 2048), 256, 0, stream>>>(wq, wq_b, (int)CC);
  wcvt<<<dim3(CC / 2048), 256, 0, stream>>>(wk, wk_b, (int)CC);
  wcvt<<<dim3(CC / 2048), 256, 0, stream>>>(wv, wv_b, (int)CC);
  wcvt<<<dim3(CC / 2048), 256, 0, stream>>>(wo, wo_b, (int)CC);
  bcat2<<<dim3(4), 256, 0, stream>>>(bq, bk, bqk, C);

  // groupnorm -> h_t [b,n,c]
  groupnorm_k<<<dim3(32, B), 256, 0, stream>>>(x, gamma, beta, h_t, C, N);

  // fused q|k : qk_t[b,n,0:512]=q, [512:1024]=k   (256^2, 64 tiles x B)
  gemm_nt256<<<dim3((N / 256) * (1024 / 256), 1, B), 512, 0, stream>>>(
      h_t, C, NC, wq_b, C, 0, qk_t, 1024, (unsigned long long)N * 1024, 0,
      C, 1.0f, 1024 / 256, bqk);
  // v : [b,co,n] = w[co,ci] * h_t[b,n,ci]^T + b[co]
  dim3 gv(C / 128, N / 128, B);
  gemm_nt<false><<<gv, 256, 0, stream>>>(wv_b, C, 0, h_t, C, NC, v_cn, N, NC,
                                         C, 1.0f, bv, nullptr, nullptr, 0);

  const float scale = 0.044194173824159216f;  // 512^-0.5
  if (s_batched) {
    // QK: S[n,m] = scale * q[n,:] . k[m,:]
    gemm_nt256<<<dim3((N / 256) * (N / 256), 1, B), 512, 0, stream>>>(
        qk_t, 1024, (unsigned long long)N * 1024, qk_t + 512, 1024,
        (unsigned long long)N * 1024, S, N, NN, 0, C, scale, N / 256, nullptr);
    softmax_rows<<<dim3(N, B), 256, 0, stream>>>(S);
    // PV split-K=2: partials [split][b][n][c] (aliases qk_t), then reduce
    gemm_nt256<<<dim3((N / 256) * (C / 256), 2, B), 512, 0, stream>>>(
        S, N, NN, v_cn, N, NC, o_part, C, NC, (unsigned long long)B * NC,
        N / 2, 1.0f, C / 256, nullptr);
    reduce_pv<<<dim3((int)(B * NC / 2048)), 256, 0, stream>>>(o_part, o_t, (int)(B * NC));
  } else {
    for (int b = 0; b < B; ++b) {
      gemm_nt256<<<dim3((N / 256) * (N / 256), 1, 1), 512, 0, stream>>>(
          qk_t + (size_t)b * N * 1024, 1024, 0, qk_t + (size_t)b * N * 1024 + 512,
          1024, 0, S, N, 0, 0, C, scale, N / 256, nullptr);
      softmax_rows<<<dim3(N, 1), 256, 0, stream>>>(S);
      // unsplit PV per batch (qk_t still holds later batches' q/k)
      gemm_nt256<<<dim3((N / 256) * (C / 256), 1, 1), 512, 0, stream>>>(
          S, N, 0, v_cn + (size_t)b * NC, N, 0, o_t + (size_t)b * NC, C, 0, 0,
          N, 1.0f, C / 256, nullptr);
    }
  }

  // out[b,co,n] = wo[co,ci] * o_t[b,n,ci]^T + bo[co] + x[b,co,n]   (fp32)
  dim3 gf(C / 128, N / 128, B);
  gemm_nt<true><<<gf, 256, 0, stream>>>(wo_b, C, 0, o_t, C, NC, d_out, N, NC,
                                        C, 1.0f, bo, nullptr, x, NC);
}